// Round 14
// baseline (52.938 us; speedup 1.0000x reference)
//
#include <hip/hip_runtime.h>

typedef __attribute__((ext_vector_type(8))) short short8v;   // 8 bf16
typedef __attribute__((ext_vector_type(4))) float f32x4;
typedef unsigned short u16t;

__device__ __forceinline__ u16t f2bf(float f) {
    union { float f; unsigned u; } v; v.f = f;
    unsigned u = v.u;
    return (u16t)((u + 0x7FFFu + ((u >> 16) & 1u)) >> 16);
}
__device__ __forceinline__ float bf2f(u16t u) {
    union { unsigned u; float f; } v; v.u = ((unsigned)u) << 16; return v.f;
}
__device__ __forceinline__ short8v cvt8(const float* p) {
    float4 lo = *(const float4*)p;
    float4 hi = *(const float4*)(p + 4);
    union { uint4 u; short8v s; } r;
    asm("v_cvt_pk_bf16_f32 %0, %1, %2" : "=v"(r.u.x) : "v"(lo.x), "v"(lo.y));
    asm("v_cvt_pk_bf16_f32 %0, %1, %2" : "=v"(r.u.y) : "v"(lo.z), "v"(lo.w));
    asm("v_cvt_pk_bf16_f32 %0, %1, %2" : "=v"(r.u.z) : "v"(hi.x), "v"(hi.y));
    asm("v_cvt_pk_bf16_f32 %0, %1, %2" : "=v"(r.u.w) : "v"(hi.z), "v"(hi.w));
    return r.s;
}
// 8 bf16 from pitch-52 LDS tile (8B-aligned): two b64 loads
__device__ __forceinline__ short8v ld52(const u16t* p) {
    union { uint2 u[2]; short8v s; } r;
    r.u[0] = *(const uint2*)(p);
    r.u[1] = *(const uint2*)(p + 4);
    return r.s;
}

struct Params {
    const float *async_fea, *sync_fea;
    const int *async_adj, *sync_adj;
    const float *Wf[10];       // aWq,aWk,aWv,aWo,aWm, sWq,sWk,sWv,sWo,sWm (fp32)
    const float *bqkv[6];      // [agg*3+mat]
    const float *bo_[2], *bm_[2];
    u16t *Wb;                  // [10][256][256] bf16
    u16t *Qb, *Kb;             // [agg][1536][256] bf16 row-major
    u16t *VTg;                 // [agg][32][256][48] bf16 (V transposed per batch)
    u16t *Eg, *ETg;            // [agg][b][h][48][48] bf16
    float *out;
};

// ---------- Launch 0: weights -> bf16 (blocks 0..319) + passthrough copy (320..511) ----------
__global__ __launch_bounds__(256) void convert_kernel(Params p)
{
    if (blockIdx.x < 320) {
        int g8 = (blockIdx.x * 256 + threadIdx.x) * 8;
        int w = g8 >> 16;
        int off = g8 & 65535;
        *(short8v*)(p.Wb + g8) = cvt8(p.Wf[w] + off);
    } else {
        // passthrough: out cols 512..767 <- async_fea, 768..1023 <- sync_fea
        int base = (blockIdx.x - 320) * 256 + threadIdx.x;   // 0..49151
        const float4* af4 = (const float4*)p.async_fea;
        const float4* sf4 = (const float4*)p.sync_fea;
        float4* out4 = (float4*)p.out;
        #pragma unroll
        for (int i = 0; i < 4; ++i) {
            int gidx = base + i * 49152;          // 0 .. 196607
            int row = gidx >> 7, jj = gidx & 127;
            const float4* src = (jj < 64) ? af4 : sf4;
            out4[row * 256 + 128 + jj] = src[row * 64 + (jj & 63)];
        }
    }
}

// ---------- Launch 1: QKV MFMA (576 blocks x 256 thr), XCD-swizzled ----------
__global__ __launch_bounds__(256) void qkv_kernel(Params p)
{
    int bid = blockIdx.x;
    int xcd = bid & 7, idx = bid >> 3;        // idx 0..71
    int agg = xcd >> 2, xcd_in = xcd & 3;
    int ct = idx % 12, rt = (idx / 12) * 4 + xcd_in;   // rt 0..23
    int wave = threadIdx.x >> 6, lane = threadIdx.x & 63;
    int l15 = lane & 15, g = lane >> 4;
    int row0 = rt * 64 + wave * 16;
    int mat = ct >> 2;
    int cbase = (ct & 3) * 64;
    const float* X = agg ? p.async_fea : p.sync_fea;
    const float* Xp = X + (row0 + l15) * 256 + g * 8;
    const u16t* Wp = p.Wb + (agg * 5 + mat) * 65536 + (cbase + l15) * 256 + g * 8;
    f32x4 acc[4] = {{0,0,0,0},{0,0,0,0},{0,0,0,0},{0,0,0,0}};
    #pragma unroll
    for (int kk = 0; kk < 8; ++kk) {
        short8v a = cvt8(Xp + kk * 32);
        #pragma unroll
        for (int j = 0; j < 4; ++j) {
            short8v b = *(const short8v*)(Wp + j * 16 * 256 + kk * 32);
            acc[j] = __builtin_amdgcn_mfma_f32_16x16x32_bf16(a, b, acc[j], 0, 0, 0);
        }
    }
    const float* bias = p.bqkv[agg * 3 + mat];
    if (mat < 2) {
        u16t* dst = ((mat == 0) ? p.Qb : p.Kb) + agg * 393216;
        #pragma unroll
        for (int j = 0; j < 4; ++j) {
            int c = cbase + j * 16 + l15;
            float bv = bias[c];
            #pragma unroll
            for (int i = 0; i < 4; ++i) {
                int row = row0 + g * 4 + i;
                dst[row * 256 + c] = f2bf(acc[j][i] + bv);
            }
        }
    } else {
        // V transposed: VTg[agg][b][d][k]
        u16t* vt = p.VTg + agg * 393216;
        #pragma unroll
        for (int j = 0; j < 4; ++j) {
            int c = cbase + j * 16 + l15;
            float bv = bias[c];
            #pragma unroll
            for (int i = 0; i < 4; ++i) {
                int row = row0 + g * 4 + i;
                vt[(row / 48) * 12288 + c * 48 + (row % 48)] = f2bf(acc[j][i] + bv);
            }
        }
    }
}

// ---------- Launch 2: scores -> E, ET bf16 (512 blocks, 192 thr), XCD-swizzled ----
__global__ __launch_bounds__(192) void scores_kernel(Params p)
{
    int bid = blockIdx.x;
    int xcd = bid & 7, idx = bid >> 3;        // idx 0..63
    int agg = xcd >> 2, xcd_in = xcd & 3;
    int h = idx & 7, b = (idx >> 3) * 4 + xcd_in;
    int qt = threadIdx.x >> 6, lane = threadIdx.x & 63;
    int l15 = lane & 15, g = lane >> 4;
    const u16t* Qp = p.Qb + agg * 393216 + (b * 48 + qt * 16 + l15) * 256 + h * 32 + g * 8;
    short8v a = *(const short8v*)Qp;
    f32x4 acc[3];
    #pragma unroll
    for (int kt = 0; kt < 3; ++kt) {
        const u16t* Kp = p.Kb + agg * 393216 + (b * 48 + kt * 16 + l15) * 256 + h * 32 + g * 8;
        short8v kb = *(const short8v*)Kp;
        f32x4 z = {0.f, 0.f, 0.f, 0.f};
        acc[kt] = __builtin_amdgcn_mfma_f32_16x16x32_bf16(a, kb, z, 0, 0, 0);
    }
    const float scale = 0.17677669529663687f;  // 1/sqrt(32)
    float sc[3][4], rm[4];
    #pragma unroll
    for (int i = 0; i < 4; ++i) {
        #pragma unroll
        for (int kt = 0; kt < 3; ++kt) sc[kt][i] = acc[kt][i] * scale;
        rm[i] = fmaxf(fmaxf(sc[0][i], sc[1][i]), sc[2][i]);
    }
    #pragma unroll
    for (int m = 1; m <= 8; m <<= 1)
        #pragma unroll
        for (int i = 0; i < 4; ++i) rm[i] = fmaxf(rm[i], __shfl_xor(rm[i], m));
    u16t* Eb  = p.Eg  + (agg * 32 + b) * 18432 + h * 2304;
    u16t* ETb = p.ETg + (agg * 32 + b) * 18432 + h * 2304;
    #pragma unroll
    for (int kt = 0; kt < 3; ++kt)
        #pragma unroll
        for (int i = 0; i < 4; ++i) {
            u16t ev = f2bf(__expf(sc[kt][i] - rm[i]));
            int q = qt * 16 + g * 4 + i, k = kt * 16 + l15;
            Eb[q * 48 + k]  = ev;
            ETb[k * 48 + q] = ev;
        }
}

// ---------- Launch 3: aggregation (256 blocks, 512 thr), XCD-swizzled ----------
// LDS 36,800 B -> 4 blocks/CU. V/E/ET/Wo/Wm read as global frags. No passthrough here.
#define IV_OFF   0          // [8*16][52] u16 = 13,312 (pool overlays after Phase B)
#define YV_OFF   13312      // 13,312
#define PL_OFF   26624      // [16][264] = 8,448
#define MSK_OFF  35072      // [16][52] = 1,664
#define CNT_OFF  36736      // 64
#define SM3_SIZE 36800
#define PO_OFF   IV_OFF     // pool 8,448 <= 13,312 (iv dead after Phase B)
#define SP 52
#define XP 264

__global__ __launch_bounds__(512) void agg_kernel(Params p)
{
    __shared__ __attribute__((aligned(16))) char sm[SM3_SIZE];
    u16t* iv_  = (u16t*)(sm + IV_OFF);
    u16t* yv_  = (u16t*)(sm + YV_OFF);
    u16t* P_l  = (u16t*)(sm + PL_OFF);
    u16t* po_  = (u16t*)(sm + PO_OFF);
    u16t* mskb = (u16t*)(sm + MSK_OFF);
    float* cnt_l = (float*)(sm + CNT_OFF);

    const int bid = blockIdx.x, tid = threadIdx.x;
    // bijective XCD map: agg0 -> XCDs 0-3, agg1 -> 4-7; all 4 tg of (agg,b) on one XCD.
    const int xcd = bid & 7, idx = bid >> 3;          // idx 0..31
    const int agg = xcd >> 2, xcd_in = xcd & 3;
    const int tg = idx >> 3, b = ((idx & 7) << 2) | xcd_in;
    const int wave = tid >> 6, lane = tid & 63;
    const int l15 = lane & 15, g = lane >> 4;
    const int row_base = b * 48 + tg * 12;

    const float* fb  = agg ? p.sync_fea  : p.async_fea;
    const int*   adj = agg ? p.async_adj : p.sync_adj;
    const u16t* Egb  = p.Eg  + (agg * 32 + b) * 18432;
    const u16t* ETb  = p.ETg + (agg * 32 + b) * 18432;
    const u16t* VTb  = p.VTg + agg * 393216 + b * 12288;

    // ---- masks ----
    for (int e = tid; e < 16 * SP; e += 512) {
        int tt = e / SP, k = e - tt * SP;
        u16t v = 0;
        if (tt < 12 && k < 48)
            v = (adj[(b * 48 + k) * 48 + tg * 12 + tt] > 0) ? (u16t)0x3F80 : (u16t)0;
        mskb[e] = v;
    }
    __syncthreads();                                             // B1
    if (tid < 12) {
        float c = 0.f;
        for (int s = 0; s < 48; ++s) c += bf2f(mskb[tid * SP + s]);
        cnt_l[tid] = c;
    }

    // ---- Phase A (MFMA): D[row][tt] = sum_k E[row][k]*m[tt][k]; iv = 1/D ----
    #pragma unroll
    for (int jj = 0; jj < 3; ++jj) {
        int rt = wave * 3 + jj;             // 0..23
        const u16t* Arow = Egb + (rt * 16 + l15) * 48;
        const u16t* Brow = mskb + l15 * SP;
        f32x4 acc = {0.f, 0.f, 0.f, 0.f};
        short8v a0 = *(const short8v*)(Arow + g * 8);
        short8v b0 = ld52(Brow + g * 8);
        acc = __builtin_amdgcn_mfma_f32_16x16x32_bf16(a0, b0, acc, 0, 0, 0);
        short8v a1 = {0,0,0,0,0,0,0,0}, b1 = {0,0,0,0,0,0,0,0};
        if (g < 2) { a1 = *(const short8v*)(Arow + 32 + g * 8); b1 = ld52(Brow + 32 + g * 8); }
        acc = __builtin_amdgcn_mfma_f32_16x16x32_bf16(a1, b1, acc, 0, 0, 0);
        #pragma unroll
        for (int i = 0; i < 4; ++i) {
            int row = rt * 16 + g * 4 + i;
            int h = row / 48, q = row - h * 48;
            float mq = bf2f(mskb[l15 * SP + q]);
            float ivv = (mq > 0.f) ? (1.f / acc[i]) : 0.f;
            iv_[(h * 16 + l15) * SP + q] = f2bf(ivv);
        }
    }
    __syncthreads();                                             // B2

    // ---- Phase B (MFMA): yv[tt][h,k] = m[k]*sum_q iv[tt][h,q]*ET[h,k,q] ----
    #pragma unroll
    for (int jj = 0; jj < 3; ++jj) {
        int job = wave * 3 + jj;            // (h, ktile)
        int h = job / 3, kt = job % 3;
        const u16t* Arow = iv_ + (h * 16 + l15) * SP;
        const u16t* Brow = ETb + (h * 48 + kt * 16 + l15) * 48;
        f32x4 acc = {0.f, 0.f, 0.f, 0.f};
        short8v a0 = ld52(Arow + g * 8);
        short8v b0 = *(const short8v*)(Brow + g * 8);
        acc = __builtin_amdgcn_mfma_f32_16x16x32_bf16(a0, b0, acc, 0, 0, 0);
        short8v a1 = {0,0,0,0,0,0,0,0}, b1 = {0,0,0,0,0,0,0,0};
        if (g < 2) { a1 = ld52(Arow + 32 + g * 8); b1 = *(const short8v*)(Brow + 32 + g * 8); }
        acc = __builtin_amdgcn_mfma_f32_16x16x32_bf16(a1, b1, acc, 0, 0, 0);
        #pragma unroll
        for (int i = 0; i < 4; ++i) {
            int tt = g * 4 + i, k = kt * 16 + l15;
            float mk = bf2f(mskb[tt * SP + k]);
            yv_[(h * 16 + tt) * SP + k] = f2bf(acc[i] * mk);
        }
    }
    __syncthreads();                                             // B3

    // ---- Phase C (MFMA): P[tt][d] = sum_k yv[tt][h,k]*VT[b][d][k] (global B) ----
    #pragma unroll
    for (int jj = 0; jj < 2; ++jj) {
        int job = wave * 2 + jj;            // 0..15: (h, dtile)
        int h = job >> 1, dt = job & 1;
        const u16t* Arow = yv_ + (h * 16 + l15) * SP;
        const u16t* Brow = VTb + (h * 32 + dt * 16 + l15) * 48;
        f32x4 acc = {0.f, 0.f, 0.f, 0.f};
        short8v a0 = ld52(Arow + g * 8);
        short8v b0 = *(const short8v*)(Brow + g * 8);
        acc = __builtin_amdgcn_mfma_f32_16x16x32_bf16(a0, b0, acc, 0, 0, 0);
        short8v a1 = {0,0,0,0,0,0,0,0}, b1 = {0,0,0,0,0,0,0,0};
        if (g < 2) { a1 = ld52(Arow + 32 + g * 8); b1 = *(const short8v*)(Brow + 32 + g * 8); }
        acc = __builtin_amdgcn_mfma_f32_16x16x32_bf16(a1, b1, acc, 0, 0, 0);
        #pragma unroll
        for (int i = 0; i < 4; ++i)
            P_l[(g * 4 + i) * XP + h * 32 + dt * 16 + l15] = f2bf(acc[i]);
    }
    __syncthreads();                                             // B4

    // ---- G1: pooled = (P@Wo^T)/cnt^2 + bo/cnt -> bf16 (Wo bf16 global) ----
    {
        const u16t* Wo = p.Wb + (agg * 5 + 3) * 65536;
        const float* bo = p.bo_[agg];
        #pragma unroll
        for (int jj = 0; jj < 2; ++jj) {
            int ct = wave * 2 + jj;
            f32x4 acc = {0.f, 0.f, 0.f, 0.f};
            const u16t* Wp = Wo + (ct * 16 + l15) * 256 + g * 8;
            #pragma unroll
            for (int kk = 0; kk < 8; ++kk) {
                short8v a = *(const short8v*)(P_l + l15 * XP + kk * 32 + g * 8);
                short8v bf = *(const short8v*)(Wp + kk * 32);
                acc = __builtin_amdgcn_mfma_f32_16x16x32_bf16(a, bf, acc, 0, 0, 0);
            }
            int c = ct * 16 + l15;
            float bov = bo[c];
            #pragma unroll
            for (int i = 0; i < 4; ++i) {
                int t = g * 4 + i;
                float val = 0.f;
                if (t < 12) {
                    float cn = cnt_l[t];
                    float i1 = (cn > 0.f) ? 1.f / cn : 0.f;
                    val = acc[i] * i1 * i1 + bov * i1;
                }
                po_[t * XP + c] = f2bf(val);
            }
        }
    }
    __syncthreads();                                             // B5

    // ---- G2: out = pooled@Wm^T + bm (or fallback) ----
    {
        const u16t* Wm = p.Wb + (agg * 5 + 4) * 65536;
        const float* bm = p.bm_[agg];
        #pragma unroll
        for (int jj = 0; jj < 2; ++jj) {
            int ct = wave * 2 + jj;
            f32x4 acc = {0.f, 0.f, 0.f, 0.f};
            const u16t* Wp = Wm + (ct * 16 + l15) * 256 + g * 8;
            #pragma unroll
            for (int kk = 0; kk < 8; ++kk) {
                short8v a = *(const short8v*)(po_ + l15 * XP + kk * 32 + g * 8);
                short8v bf = *(const short8v*)(Wp + kk * 32);
                acc = __builtin_amdgcn_mfma_f32_16x16x32_bf16(a, bf, acc, 0, 0, 0);
            }
            int c = ct * 16 + l15;
            float bmv = bm[c];
            #pragma unroll
            for (int i = 0; i < 4; ++i) {
                int t = g * 4 + i;
                if (t < 12) {
                    int grow = row_base + t;
                    float cn = cnt_l[t];
                    float val = (cn > 0.f) ? (acc[i] + bmv) : fb[grow * 256 + c];
                    p.out[grow * 1024 + agg * 256 + c] = val;
                }
            }
        }
    }
}

extern "C" void kernel_launch(void* const* d_in, const int* in_sizes, int n_in,
                              void* d_out, int out_size, void* d_ws, size_t ws_size,
                              hipStream_t stream)
{
    Params p;
    p.async_fea = (const float*)d_in[0];
    p.sync_fea  = (const float*)d_in[1];
    p.async_adj = (const int*)d_in[2];
    p.sync_adj  = (const int*)d_in[3];
    p.Wf[0] = (const float*)d_in[4];   // aWq
    p.Wf[1] = (const float*)d_in[6];   // aWk
    p.Wf[2] = (const float*)d_in[8];   // aWv
    p.Wf[3] = (const float*)d_in[10];  // aWo
    p.Wf[4] = (const float*)d_in[12];  // aWm
    p.Wf[5] = (const float*)d_in[14];  // sWq
    p.Wf[6] = (const float*)d_in[16];  // sWk
    p.Wf[7] = (const float*)d_in[18];  // sWv
    p.Wf[8] = (const float*)d_in[20];  // sWo
    p.Wf[9] = (const float*)d_in[22];  // sWm
    p.bqkv[0] = (const float*)d_in[5];   // abq
    p.bqkv[1] = (const float*)d_in[7];   // abk
    p.bqkv[2] = (const float*)d_in[9];   // abv
    p.bqkv[3] = (const float*)d_in[15];  // sbq
    p.bqkv[4] = (const float*)d_in[17];  // sbk
    p.bqkv[5] = (const float*)d_in[19];  // sbv
    p.bo_[0] = (const float*)d_in[11];   // abo
    p.bo_[1] = (const float*)d_in[21];   // sbo
    p.bm_[0] = (const float*)d_in[13];   // abm
    p.bm_[1] = (const float*)d_in[23];   // sbm

    u16t* us = (u16t*)d_ws;
    p.Wb  = us;                    // 655,360
    p.Qb  = p.Wb + 655360;         // 786,432
    p.Kb  = p.Qb + 786432;         // 786,432
    p.VTg = p.Kb + 786432;         // 786,432
    p.Eg  = p.VTg + 786432;        // 1,179,648
    p.ETg = p.Eg + 1179648;        // 1,179,648
    p.out = (float*)d_out;

    convert_kernel<<<512, 256, 0, stream>>>(p);
    qkv_kernel<<<576, 256, 0, stream>>>(p);
    scores_kernel<<<512, 192, 0, stream>>>(p);
    agg_kernel<<<256, 512, 0, stream>>>(p);
}

// Round 15
// 50.672 us; speedup vs baseline: 1.0447x; 1.0447x over previous
//
#include <hip/hip_runtime.h>

typedef __attribute__((ext_vector_type(8))) short short8v;   // 8 bf16
typedef __attribute__((ext_vector_type(4))) float f32x4;
typedef unsigned short u16t;

__device__ __forceinline__ u16t f2bf(float f) {
    union { float f; unsigned u; } v; v.f = f;
    unsigned u = v.u;
    return (u16t)((u + 0x7FFFu + ((u >> 16) & 1u)) >> 16);
}
__device__ __forceinline__ float bf2f(u16t u) {
    union { unsigned u; float f; } v; v.u = ((unsigned)u) << 16; return v.f;
}
__device__ __forceinline__ short8v cvt8(const float* p) {
    float4 lo = *(const float4*)p;
    float4 hi = *(const float4*)(p + 4);
    union { uint4 u; short8v s; } r;
    asm("v_cvt_pk_bf16_f32 %0, %1, %2" : "=v"(r.u.x) : "v"(lo.x), "v"(lo.y));
    asm("v_cvt_pk_bf16_f32 %0, %1, %2" : "=v"(r.u.y) : "v"(lo.z), "v"(lo.w));
    asm("v_cvt_pk_bf16_f32 %0, %1, %2" : "=v"(r.u.z) : "v"(hi.x), "v"(hi.y));
    asm("v_cvt_pk_bf16_f32 %0, %1, %2" : "=v"(r.u.w) : "v"(hi.z), "v"(hi.w));
    return r.s;
}
// 8 bf16 from pitch-52 LDS tile (8B-aligned): two b64 loads
__device__ __forceinline__ short8v ld52(const u16t* p) {
    union { uint2 u[2]; short8v s; } r;
    r.u[0] = *(const uint2*)(p);
    r.u[1] = *(const uint2*)(p + 4);
    return r.s;
}

struct Params {
    const float *async_fea, *sync_fea;
    const int *async_adj, *sync_adj;
    const float *Wf[10];       // aWq,aWk,aWv,aWo,aWm, sWq,sWk,sWv,sWo,sWm (fp32)
    const float *bqkv[6];      // [agg*3+mat]
    const float *bo_[2], *bm_[2];
    u16t *Wb;                  // [10][256][256] bf16
    u16t *Qb, *Kb;             // [agg][1536][256] bf16 row-major
    u16t *VTg;                 // [agg][32][256][48] bf16 (V transposed per batch)
    u16t *Eg, *ETg;            // [agg][b][h][48][48] bf16
    float *out;
};

// ---------- Launch 0: weights -> bf16 ----------
__global__ __launch_bounds__(256) void convert_kernel(Params p)
{
    int g8 = (blockIdx.x * 256 + threadIdx.x) * 8;
    int w = g8 >> 16;
    int off = g8 & 65535;
    *(short8v*)(p.Wb + g8) = cvt8(p.Wf[w] + off);
}

// ---------- Launch 1: QKV MFMA (576 blocks x 256 thr), XCD-swizzled ----------
// bid&7 -> XCD (HW round-robin). agg = XCD-half; same-XCD consecutive blocks share rt.
__global__ __launch_bounds__(256) void qkv_kernel(Params p)
{
    int bid = blockIdx.x;
    int xcd = bid & 7, idx = bid >> 3;        // idx 0..71
    int agg = xcd >> 2, xcd_in = xcd & 3;
    int ct = idx % 12, rt = (idx / 12) * 4 + xcd_in;   // rt 0..23
    int wave = threadIdx.x >> 6, lane = threadIdx.x & 63;
    int l15 = lane & 15, g = lane >> 4;
    int row0 = rt * 64 + wave * 16;
    int mat = ct >> 2;
    int cbase = (ct & 3) * 64;
    const float* X = agg ? p.async_fea : p.sync_fea;
    const float* Xp = X + (row0 + l15) * 256 + g * 8;
    const u16t* Wp = p.Wb + (agg * 5 + mat) * 65536 + (cbase + l15) * 256 + g * 8;
    f32x4 acc[4] = {{0,0,0,0},{0,0,0,0},{0,0,0,0},{0,0,0,0}};
    #pragma unroll
    for (int kk = 0; kk < 8; ++kk) {
        short8v a = cvt8(Xp + kk * 32);
        #pragma unroll
        for (int j = 0; j < 4; ++j) {
            short8v b = *(const short8v*)(Wp + j * 16 * 256 + kk * 32);
            acc[j] = __builtin_amdgcn_mfma_f32_16x16x32_bf16(a, b, acc[j], 0, 0, 0);
        }
    }
    const float* bias = p.bqkv[agg * 3 + mat];
    if (mat < 2) {
        u16t* dst = ((mat == 0) ? p.Qb : p.Kb) + agg * 393216;
        #pragma unroll
        for (int j = 0; j < 4; ++j) {
            int c = cbase + j * 16 + l15;
            float bv = bias[c];
            #pragma unroll
            for (int i = 0; i < 4; ++i) {
                int row = row0 + g * 4 + i;
                dst[row * 256 + c] = f2bf(acc[j][i] + bv);
            }
        }
    } else {
        // V transposed: VTg[agg][b][d][k]
        u16t* vt = p.VTg + agg * 393216;
        #pragma unroll
        for (int j = 0; j < 4; ++j) {
            int c = cbase + j * 16 + l15;
            float bv = bias[c];
            #pragma unroll
            for (int i = 0; i < 4; ++i) {
                int row = row0 + g * 4 + i;
                vt[(row / 48) * 12288 + c * 48 + (row % 48)] = f2bf(acc[j][i] + bv);
            }
        }
    }
}

// ---------- Launch 2: scores -> E, ET bf16 (512 blocks, 192 thr), XCD-swizzled ----
__global__ __launch_bounds__(192) void scores_kernel(Params p)
{
    int bid = blockIdx.x;
    int xcd = bid & 7, idx = bid >> 3;        // idx 0..63
    int agg = xcd >> 2, xcd_in = xcd & 3;
    int h = idx & 7, b = (idx >> 3) * 4 + xcd_in;
    int qt = threadIdx.x >> 6, lane = threadIdx.x & 63;
    int l15 = lane & 15, g = lane >> 4;
    const u16t* Qp = p.Qb + agg * 393216 + (b * 48 + qt * 16 + l15) * 256 + h * 32 + g * 8;
    short8v a = *(const short8v*)Qp;
    f32x4 acc[3];
    #pragma unroll
    for (int kt = 0; kt < 3; ++kt) {
        const u16t* Kp = p.Kb + agg * 393216 + (b * 48 + kt * 16 + l15) * 256 + h * 32 + g * 8;
        short8v kb = *(const short8v*)Kp;
        f32x4 z = {0.f, 0.f, 0.f, 0.f};
        acc[kt] = __builtin_amdgcn_mfma_f32_16x16x32_bf16(a, kb, z, 0, 0, 0);
    }
    const float scale = 0.17677669529663687f;  // 1/sqrt(32)
    float sc[3][4], rm[4];
    #pragma unroll
    for (int i = 0; i < 4; ++i) {
        #pragma unroll
        for (int kt = 0; kt < 3; ++kt) sc[kt][i] = acc[kt][i] * scale;
        rm[i] = fmaxf(fmaxf(sc[0][i], sc[1][i]), sc[2][i]);
    }
    #pragma unroll
    for (int m = 1; m <= 8; m <<= 1)
        #pragma unroll
        for (int i = 0; i < 4; ++i) rm[i] = fmaxf(rm[i], __shfl_xor(rm[i], m));
    u16t* Eb  = p.Eg  + (agg * 32 + b) * 18432 + h * 2304;
    u16t* ETb = p.ETg + (agg * 32 + b) * 18432 + h * 2304;
    #pragma unroll
    for (int kt = 0; kt < 3; ++kt)
        #pragma unroll
        for (int i = 0; i < 4; ++i) {
            u16t ev = f2bf(__expf(sc[kt][i] - rm[i]));
            int q = qt * 16 + g * 4 + i, k = kt * 16 + l15;
            Eb[q * 48 + k]  = ev;
            ETb[k * 48 + q] = ev;
        }
}

// ---------- Launch 3: aggregation (256 blocks, 512 thr), XCD-swizzled ----------
// LDS 36,800 B -> 4 blocks/CU (32 waves/CU). V/E/ET/Wo/Wm read as global frags.
#define IV_OFF   0          // [8*16][52] u16 = 13,312 (pool overlays after Phase B)
#define YV_OFF   13312      // 13,312
#define PL_OFF   26624      // [16][264] = 8,448
#define MSK_OFF  35072      // [16][52] = 1,664
#define CNT_OFF  36736      // 64
#define SM3_SIZE 36800
#define PO_OFF   IV_OFF     // pool 8,448 <= 13,312 (iv dead after Phase B)
#define SP 52
#define XP 264

__global__ __launch_bounds__(512) void agg_kernel(Params p)
{
    __shared__ __attribute__((aligned(16))) char sm[SM3_SIZE];
    u16t* iv_  = (u16t*)(sm + IV_OFF);
    u16t* yv_  = (u16t*)(sm + YV_OFF);
    u16t* P_l  = (u16t*)(sm + PL_OFF);
    u16t* po_  = (u16t*)(sm + PO_OFF);
    u16t* mskb = (u16t*)(sm + MSK_OFF);
    float* cnt_l = (float*)(sm + CNT_OFF);

    const int bid = blockIdx.x, tid = threadIdx.x;
    // bijective XCD map: agg0 -> XCDs 0-3, agg1 -> 4-7; all 4 tg of (agg,b) on one XCD.
    const int xcd = bid & 7, idx = bid >> 3;          // idx 0..31
    const int agg = xcd >> 2, xcd_in = xcd & 3;
    const int tg = idx >> 3, b = ((idx & 7) << 2) | xcd_in;
    const int wave = tid >> 6, lane = tid & 63;
    const int l15 = lane & 15, g = lane >> 4;
    const int row_base = b * 48 + tg * 12;

    const float* fb  = agg ? p.sync_fea  : p.async_fea;
    const int*   adj = agg ? p.async_adj : p.sync_adj;
    const u16t* Egb  = p.Eg  + (agg * 32 + b) * 18432;
    const u16t* ETb  = p.ETg + (agg * 32 + b) * 18432;
    const u16t* VTb  = p.VTg + agg * 393216 + b * 12288;

    // ---- masks + passthrough ----
    for (int e = tid; e < 16 * SP; e += 512) {
        int tt = e / SP, k = e - tt * SP;
        u16t v = 0;
        if (tt < 12 && k < 48)
            v = (adj[(b * 48 + k) * 48 + tg * 12 + tt] > 0) ? (u16t)0x3F80 : (u16t)0;
        mskb[e] = v;
    }
    {
        const float4* fb4 = (const float4*)fb;
        float4* out4 = (float4*)p.out;
        for (int e = tid; e < 768; e += 512) {
            int r = e >> 6, c = e & 63;
            out4[(row_base + r) * 256 + 128 + agg * 64 + c] =
                fb4[(row_base + r) * 64 + c];
        }
    }
    __syncthreads();                                             // B1
    if (tid < 12) {
        float c = 0.f;
        for (int s = 0; s < 48; ++s) c += bf2f(mskb[tid * SP + s]);
        cnt_l[tid] = c;
    }

    // ---- Phase A (MFMA): D[row][tt] = sum_k E[row][k]*m[tt][k]; iv = 1/D ----
    #pragma unroll
    for (int jj = 0; jj < 3; ++jj) {
        int rt = wave * 3 + jj;             // 0..23
        const u16t* Arow = Egb + (rt * 16 + l15) * 48;
        const u16t* Brow = mskb + l15 * SP;
        f32x4 acc = {0.f, 0.f, 0.f, 0.f};
        short8v a0 = *(const short8v*)(Arow + g * 8);
        short8v b0 = ld52(Brow + g * 8);
        acc = __builtin_amdgcn_mfma_f32_16x16x32_bf16(a0, b0, acc, 0, 0, 0);
        short8v a1 = {0,0,0,0,0,0,0,0}, b1 = {0,0,0,0,0,0,0,0};
        if (g < 2) { a1 = *(const short8v*)(Arow + 32 + g * 8); b1 = ld52(Brow + 32 + g * 8); }
        acc = __builtin_amdgcn_mfma_f32_16x16x32_bf16(a1, b1, acc, 0, 0, 0);
        #pragma unroll
        for (int i = 0; i < 4; ++i) {
            int row = rt * 16 + g * 4 + i;
            int h = row / 48, q = row - h * 48;
            float mq = bf2f(mskb[l15 * SP + q]);
            float ivv = (mq > 0.f) ? (1.f / acc[i]) : 0.f;
            iv_[(h * 16 + l15) * SP + q] = f2bf(ivv);
        }
    }
    __syncthreads();                                             // B2

    // ---- Phase B (MFMA): yv[tt][h,k] = m[k]*sum_q iv[tt][h,q]*ET[h,k,q] ----
    #pragma unroll
    for (int jj = 0; jj < 3; ++jj) {
        int job = wave * 3 + jj;            // (h, ktile)
        int h = job / 3, kt = job % 3;
        const u16t* Arow = iv_ + (h * 16 + l15) * SP;
        const u16t* Brow = ETb + (h * 48 + kt * 16 + l15) * 48;
        f32x4 acc = {0.f, 0.f, 0.f, 0.f};
        short8v a0 = ld52(Arow + g * 8);
        short8v b0 = *(const short8v*)(Brow + g * 8);
        acc = __builtin_amdgcn_mfma_f32_16x16x32_bf16(a0, b0, acc, 0, 0, 0);
        short8v a1 = {0,0,0,0,0,0,0,0}, b1 = {0,0,0,0,0,0,0,0};
        if (g < 2) { a1 = ld52(Arow + 32 + g * 8); b1 = *(const short8v*)(Brow + 32 + g * 8); }
        acc = __builtin_amdgcn_mfma_f32_16x16x32_bf16(a1, b1, acc, 0, 0, 0);
        #pragma unroll
        for (int i = 0; i < 4; ++i) {
            int tt = g * 4 + i, k = kt * 16 + l15;
            float mk = bf2f(mskb[tt * SP + k]);
            yv_[(h * 16 + tt) * SP + k] = f2bf(acc[i] * mk);
        }
    }
    __syncthreads();                                             // B3

    // ---- Phase C (MFMA): P[tt][d] = sum_k yv[tt][h,k]*VT[b][d][k] (global B) ----
    #pragma unroll
    for (int jj = 0; jj < 2; ++jj) {
        int job = wave * 2 + jj;            // 0..15: (h, dtile)
        int h = job >> 1, dt = job & 1;
        const u16t* Arow = yv_ + (h * 16 + l15) * SP;
        const u16t* Brow = VTb + (h * 32 + dt * 16 + l15) * 48;
        f32x4 acc = {0.f, 0.f, 0.f, 0.f};
        short8v a0 = ld52(Arow + g * 8);
        short8v b0 = *(const short8v*)(Brow + g * 8);
        acc = __builtin_amdgcn_mfma_f32_16x16x32_bf16(a0, b0, acc, 0, 0, 0);
        short8v a1 = {0,0,0,0,0,0,0,0}, b1 = {0,0,0,0,0,0,0,0};
        if (g < 2) { a1 = ld52(Arow + 32 + g * 8); b1 = *(const short8v*)(Brow + 32 + g * 8); }
        acc = __builtin_amdgcn_mfma_f32_16x16x32_bf16(a1, b1, acc, 0, 0, 0);
        #pragma unroll
        for (int i = 0; i < 4; ++i)
            P_l[(g * 4 + i) * XP + h * 32 + dt * 16 + l15] = f2bf(acc[i]);
    }
    __syncthreads();                                             // B4

    // ---- G1: pooled = (P@Wo^T)/cnt^2 + bo/cnt -> bf16 (Wo bf16 global) ----
    {
        const u16t* Wo = p.Wb + (agg * 5 + 3) * 65536;
        const float* bo = p.bo_[agg];
        #pragma unroll
        for (int jj = 0; jj < 2; ++jj) {
            int ct = wave * 2 + jj;
            f32x4 acc = {0.f, 0.f, 0.f, 0.f};
            const u16t* Wp = Wo + (ct * 16 + l15) * 256 + g * 8;
            #pragma unroll
            for (int kk = 0; kk < 8; ++kk) {
                short8v a = *(const short8v*)(P_l + l15 * XP + kk * 32 + g * 8);
                short8v bf = *(const short8v*)(Wp + kk * 32);
                acc = __builtin_amdgcn_mfma_f32_16x16x32_bf16(a, bf, acc, 0, 0, 0);
            }
            int c = ct * 16 + l15;
            float bov = bo[c];
            #pragma unroll
            for (int i = 0; i < 4; ++i) {
                int t = g * 4 + i;
                float val = 0.f;
                if (t < 12) {
                    float cn = cnt_l[t];
                    float i1 = (cn > 0.f) ? 1.f / cn : 0.f;
                    val = acc[i] * i1 * i1 + bov * i1;
                }
                po_[t * XP + c] = f2bf(val);
            }
        }
    }
    __syncthreads();                                             // B5

    // ---- G2: out = pooled@Wm^T + bm (or fallback) ----
    {
        const u16t* Wm = p.Wb + (agg * 5 + 4) * 65536;
        const float* bm = p.bm_[agg];
        #pragma unroll
        for (int jj = 0; jj < 2; ++jj) {
            int ct = wave * 2 + jj;
            f32x4 acc = {0.f, 0.f, 0.f, 0.f};
            const u16t* Wp = Wm + (ct * 16 + l15) * 256 + g * 8;
            #pragma unroll
            for (int kk = 0; kk < 8; ++kk) {
                short8v a = *(const short8v*)(po_ + l15 * XP + kk * 32 + g * 8);
                short8v bf = *(const short8v*)(Wp + kk * 32);
                acc = __builtin_amdgcn_mfma_f32_16x16x32_bf16(a, bf, acc, 0, 0, 0);
            }
            int c = ct * 16 + l15;
            float bmv = bm[c];
            #pragma unroll
            for (int i = 0; i < 4; ++i) {
                int t = g * 4 + i;
                if (t < 12) {
                    int grow = row_base + t;
                    float cn = cnt_l[t];
                    float val = (cn > 0.f) ? (acc[i] + bmv) : fb[grow * 256 + c];
                    p.out[grow * 1024 + agg * 256 + c] = val;
                }
            }
        }
    }
}

extern "C" void kernel_launch(void* const* d_in, const int* in_sizes, int n_in,
                              void* d_out, int out_size, void* d_ws, size_t ws_size,
                              hipStream_t stream)
{
    Params p;
    p.async_fea = (const float*)d_in[0];
    p.sync_fea  = (const float*)d_in[1];
    p.async_adj = (const int*)d_in[2];
    p.sync_adj  = (const int*)d_in[3];
    p.Wf[0] = (const float*)d_in[4];   // aWq
    p.Wf[1] = (const float*)d_in[6];   // aWk
    p.Wf[2] = (const float*)d_in[8];   // aWv
    p.Wf[3] = (const float*)d_in[10];  // aWo
    p.Wf[4] = (const float*)d_in[12];  // aWm
    p.Wf[5] = (const float*)d_in[14];  // sWq
    p.Wf[6] = (const float*)d_in[16];  // sWk
    p.Wf[7] = (const float*)d_in[18];  // sWv
    p.Wf[8] = (const float*)d_in[20];  // sWo
    p.Wf[9] = (const float*)d_in[22];  // sWm
    p.bqkv[0] = (const float*)d_in[5];   // abq
    p.bqkv[1] = (const float*)d_in[7];   // abk
    p.bqkv[2] = (const float*)d_in[9];   // abv
    p.bqkv[3] = (const float*)d_in[15];  // sbq
    p.bqkv[4] = (const float*)d_in[17];  // sbk
    p.bqkv[5] = (const float*)d_in[19];  // sbv
    p.bo_[0] = (const float*)d_in[11];   // abo
    p.bo_[1] = (const float*)d_in[21];   // sbo
    p.bm_[0] = (const float*)d_in[13];   // abm
    p.bm_[1] = (const float*)d_in[23];   // sbm

    u16t* us = (u16t*)d_ws;
    p.Wb  = us;                    // 655,360
    p.Qb  = p.Wb + 655360;         // 786,432
    p.Kb  = p.Qb + 786432;         // 786,432
    p.VTg = p.Kb + 786432;         // 786,432
    p.Eg  = p.VTg + 786432;        // 1,179,648
    p.ETg = p.Eg + 1179648;        // 1,179,648
    p.out = (float*)d_out;

    convert_kernel<<<320, 256, 0, stream>>>(p);
    qkv_kernel<<<576, 256, 0, stream>>>(p);
    scores_kernel<<<512, 192, 0, stream>>>(p);
    agg_kernel<<<256, 512, 0, stream>>>(p);
}